// Round 11
// baseline (229.540 us; speedup 1.0000x reference)
//
#include <hip/hip_runtime.h>
#include <hip/hip_bf16.h>
#include <hip/hip_fp16.h>
#include <math.h>

#define B_ 8
#define N_ 2048
#define F_ 128

typedef __attribute__((ext_vector_type(8))) _Float16 half8;
typedef __attribute__((ext_vector_type(4))) float f32x4;

// ---------------------------------------------------------------------------
// Kernel 1: Wh = h @ W^T (fp32), fp16 B-frag swizzled out; exact fp32 sv/tv.
// WhH layout: element (b, j, o) at ((b*64 + j/32)*128 + o)*32 + ((j/8)%4)*8
// + (j%8)  -> each 32-j chunk is one contiguous 8 KB block.
// ---------------------------------------------------------------------------
__global__ __launch_bounds__(256) void k_gemm(
    const float* __restrict__ h, const float* __restrict__ W,
    const float* __restrict__ a,
    _Float16* __restrict__ WhH, float* __restrict__ sv, float* __restrict__ tv)
{
    __shared__ float h_s[64][129];
    __shared__ float Wt[128][68];
    __shared__ float wsm[128], wtm[128];
    __shared__ float sred[64][4], tred[64][4];

    const int t = threadIdx.x;
    const int rowblk = blockIdx.x >> 1;
    const int ohalf  = blockIdx.x & 1;
    const int r0 = rowblk * 64;

    {
        const int f = (t & 31) * 4;
        #pragma unroll
        for (int it = 0; it < 8; ++it) {
            const int r = (t >> 5) + it * 8;
            float4 v = *(const float4*)&h[(size_t)(r0 + r) * F_ + f];
            h_s[r][f] = v.x; h_s[r][f + 1] = v.y;
            h_s[r][f + 2] = v.z; h_s[r][f + 3] = v.w;
        }
    }
    {
        const int f = (t & 31) * 4;
        #pragma unroll
        for (int it = 0; it < 8; ++it) {
            const int o = (t >> 5) + it * 8;
            float4 v = *(const float4*)&W[(size_t)(ohalf * 64 + o) * F_ + f];
            Wt[f][o] = v.x; Wt[f + 1][o] = v.y;
            Wt[f + 2][o] = v.z; Wt[f + 3][o] = v.w;
        }
    }
    {
        const int f = t & 127;
        const int which = t >> 7;
        const float* av = a + which * 128;
        float acc = 0.f;
        for (int o = 0; o < 128; ++o)
            acc += W[(size_t)o * F_ + f] * av[o];
        if (which == 0) wsm[f] = acc; else wtm[f] = acc;
    }
    __syncthreads();

    const int o4 = t & 15;
    const int r4 = t >> 4;
    float acc[4][4];
    #pragma unroll
    for (int i = 0; i < 4; ++i)
        #pragma unroll
        for (int j = 0; j < 4; ++j) acc[i][j] = 0.f;

    #pragma unroll 4
    for (int k = 0; k < 128; ++k) {
        float4 w = *(const float4*)&Wt[k][o4 * 4];
        float h0 = h_s[r4 * 4 + 0][k];
        float h1 = h_s[r4 * 4 + 1][k];
        float h2 = h_s[r4 * 4 + 2][k];
        float h3 = h_s[r4 * 4 + 3][k];
        acc[0][0] += h0 * w.x; acc[0][1] += h0 * w.y; acc[0][2] += h0 * w.z; acc[0][3] += h0 * w.w;
        acc[1][0] += h1 * w.x; acc[1][1] += h1 * w.y; acc[1][2] += h1 * w.z; acc[1][3] += h1 * w.w;
        acc[2][0] += h2 * w.x; acc[2][1] += h2 * w.y; acc[2][2] += h2 * w.z; acc[2][3] += h2 * w.w;
        acc[3][0] += h3 * w.x; acc[3][1] += h3 * w.y; acc[3][2] += h3 * w.z; acc[3][3] += h3 * w.w;
    }

    {
        const int Rbase = r0 + r4 * 4;
        const int b    = Rbase >> 11;
        const int jj   = Rbase & 2047;
        const int jblk = jj >> 5;
        const int k8   = (jj >> 3) & 3;
        const int kk   = jj & 7;
        #pragma unroll
        for (int jo = 0; jo < 4; ++jo) {
            const int o = ohalf * 64 + o4 * 4 + jo;
            size_t off = ((size_t)(b * 64 + jblk) * 128 + o) * 32 + k8 * 8 + kk;
            union { _Float16 x[4]; uint2 u; } pk;
            pk.x[0] = (_Float16)acc[0][jo];
            pk.x[1] = (_Float16)acc[1][jo];
            pk.x[2] = (_Float16)acc[2][jo];
            pk.x[3] = (_Float16)acc[3][jo];
            *(uint2*)(WhH + off) = pk.u;
        }
    }

    {
        const int r = t & 63, part = t >> 6;
        float as_ = 0.f, at_ = 0.f;
        const int kb = part * 32;
        for (int k = kb; k < kb + 32; ++k) {
            float hv = h_s[r][k];
            as_ += hv * wsm[k];
            at_ += hv * wtm[k];
        }
        sred[r][part] = as_; tred[r][part] = at_;
    }
    __syncthreads();
    if (ohalf == 0 && t < 64) {
        sv[r0 + t] = sred[t][0] + sred[t][1] + sred[t][2] + sred[t][3];
        tv[r0 + t] = tred[t][0] + tred[t][1] + tred[t][2] + tred[t][3];
    }
}

// ---------------------------------------------------------------------------
// Kernel 2: flash-GAT, factorized softmax, DEPTH-2 register pipeline.
// 512 blocks = 8 batch x 64 i-tiles(32 rows); wave wv owns j-slice
// [wv*512,+512) (16 chunks of 32); two A-frags per wave (rows m_, m_+16)
// share every B-frag load.  B-frags AND adj prefetched TWO iterations
// ahead into parity-slot register buffers; #pragma unroll 2 keeps slot
// indices constant without letting full unroll sink the loads.
// p = adj ? (E_j>Ethr_i ? C_i*E_j : D_i*F_j) : 0, E/F staged per block.
// Direct out via two-pass 32 KB LDS reduce.
// ---------------------------------------------------------------------------
__global__ __launch_bounds__(256, 2) void k_attn(
    const _Float16* __restrict__ WhH, const float* __restrict__ sv,
    const float* __restrict__ tv, const int* __restrict__ adj,
    float* __restrict__ out)
{
    __shared__ float  redO[4][16][128];   // 32 KB (two-pass reuse)
    __shared__ float  redL[4][32];
    __shared__ float2 efS[2048];          // 16 KB: (E_j, F_j)
    __shared__ float  tmr[4];

    const int t  = threadIdx.x;
    const int b  = blockIdx.x & 7;        // XCD-swizzle heuristic
    const int i0 = (blockIdx.x >> 3) * 32;
    const float* tb = tv + ((size_t)b << 11);

    // phase 1: per-batch tmax (t-values kept in regs)
    float tv8[8];
    float tm = -INFINITY;
    #pragma unroll
    for (int k = 0; k < 8; ++k) {
        tv8[k] = tb[t + k * 256];
        tm = fmaxf(tm, tv8[k]);
    }
    #pragma unroll
    for (int k = 32; k; k >>= 1) tm = fmaxf(tm, __shfl_xor(tm, k, 64));
    if ((t & 63) == 0) tmr[t >> 6] = tm;
    __syncthreads();
    const float tmax = fmaxf(fmaxf(tmr[0], tmr[1]), fmaxf(tmr[2], tmr[3]));

    // phase 2: E/F table
    #pragma unroll
    for (int k = 0; k < 8; ++k) {
        float d = tv8[k] - tmax;
        efS[t + k * 256] = make_float2(__expf(d), __expf(0.2f * d));
    }

    const int wv   = t >> 6;
    const int lane = t & 63;
    const int m_   = lane & 15;
    const int q_   = lane >> 4;
    const int jbase = wv * 512;

    const int girow0 = (b << 11) + i0 + m_;
    const int girow1 = girow0 + 16;
    const float s0 = sv[girow0];
    const float s1 = sv[girow1];
    const float M0 = fmaxf(s0 + tmax, 0.f);
    const float M1 = fmaxf(s1 + tmax, 0.f);
    const float C0 = __expf(s0 + tmax - M0), D0 = __expf(0.2f * (s0 + tmax) - M0);
    const float C1 = __expf(s1 + tmax - M1), D1 = __expf(0.2f * (s1 + tmax) - M1);
    const float T0 = __expf(-s0 - tmax);
    const float T1 = __expf(-s1 - tmax);

    const int* arow0 = adj + ((size_t)girow0 << 11) + jbase + q_ * 8;
    const int* arow1 = adj + ((size_t)girow1 << 11) + jbase + q_ * 8;
    const _Float16* whc = WhH + (((size_t)b * 64 + wv * 16) << 12)
                        + (size_t)m_ * 32 + q_ * 8;

    f32x4 acc0[8], acc1[8];
    #pragma unroll
    for (int n = 0; n < 8; ++n) {
        acc0[n] = (f32x4){0.f, 0.f, 0.f, 0.f};
        acc1[n] = (f32x4){0.f, 0.f, 0.f, 0.f};
    }
    float lsum0 = 0.f, lsum1 = 0.f;

    // depth-2 register pipeline buffers (parity slots)
    int4  pa0L[2], pa0H[2], pa1L[2], pa1H[2];
    half8 pb[2][8];
    #pragma unroll
    for (int c = 0; c < 2; ++c) {
        pa0L[c] = *(const int4*)(arow0 + c * 32);
        pa0H[c] = *(const int4*)(arow0 + c * 32 + 4);
        pa1L[c] = *(const int4*)(arow1 + c * 32);
        pa1H[c] = *(const int4*)(arow1 + c * 32 + 4);
        const _Float16* wb = whc + ((size_t)c << 12);
        #pragma unroll
        for (int n = 0; n < 8; ++n)
            pb[c][n] = *(const half8*)(wb + n * 512);
    }

    __syncthreads();   // efS visible

    #pragma unroll 2
    for (int jj = 0; jj < 16; ++jj) {
        const int s  = jj & 1;
        const int nx = (jj + 2) & 15;                 // wrap: harmless

        // consume current slot into locals
        int4 a0L = pa0L[s], a0H = pa0H[s];
        int4 a1L = pa1L[s], a1H = pa1H[s];
        half8 bf[8];
        #pragma unroll
        for (int n = 0; n < 8; ++n) bf[n] = pb[s][n];

        // refill slot s with iteration jj+2's data (2 iterations in flight)
        pa0L[s] = *(const int4*)(arow0 + nx * 32);
        pa0H[s] = *(const int4*)(arow0 + nx * 32 + 4);
        pa1L[s] = *(const int4*)(arow1 + nx * 32);
        pa1H[s] = *(const int4*)(arow1 + nx * 32 + 4);
        const _Float16* wn = whc + ((size_t)nx << 12);
        #pragma unroll
        for (int n = 0; n < 8; ++n)
            pb[s][n] = *(const half8*)(wn + n * 512);

        // E/F for this lane's 8 k's
        const float4* efp = (const float4*)&efS[jbase + jj * 32 + q_ * 8];
        float4 v0 = efp[0], v1 = efp[1], v2 = efp[2], v3 = efp[3];
        float Ek[8] = {v0.x, v0.z, v1.x, v1.z, v2.x, v2.z, v3.x, v3.z};
        float Fk[8] = {v0.y, v0.w, v1.y, v1.w, v2.y, v2.w, v3.y, v3.w};
        int  a0k[8] = {a0L.x, a0L.y, a0L.z, a0L.w, a0H.x, a0H.y, a0H.z, a0H.w};
        int  a1k[8] = {a1L.x, a1L.y, a1L.z, a1L.w, a1H.x, a1H.y, a1H.z, a1H.w};

        half8 af0, af1;
        #pragma unroll
        for (int k = 0; k < 8; ++k) {
            float p0 = (Ek[k] > T0) ? C0 * Ek[k] : D0 * Fk[k];
            p0 = a0k[k] ? p0 : 0.f;
            float p1 = (Ek[k] > T1) ? C1 * Ek[k] : D1 * Fk[k];
            p1 = a1k[k] ? p1 : 0.f;
            lsum0 += p0; lsum1 += p1;
            af0[k] = (_Float16)p0; af1[k] = (_Float16)p1;
        }

        #pragma unroll
        for (int n = 0; n < 8; ++n) {
            acc0[n] = __builtin_amdgcn_mfma_f32_16x16x32_f16(af0, bf[n], acc0[n], 0, 0, 0);
            acc1[n] = __builtin_amdgcn_mfma_f32_16x16x32_f16(af1, bf[n], acc1[n], 0, 0, 0);
        }
    }

    // partial l over k-lanes (bits 4,5)
    lsum0 += __shfl_xor(lsum0, 16, 64); lsum0 += __shfl_xor(lsum0, 32, 64);
    lsum1 += __shfl_xor(lsum1, 16, 64); lsum1 += __shfl_xor(lsum1, 32, 64);
    if (q_ == 0) { redL[wv][m_] = lsum0; redL[wv][16 + m_] = lsum1; }
    __syncthreads();

    // two-pass cross-wave reduce + direct out.
    // C/D layout: row = q_*4 + r, col = n*16 + m_.
    #pragma unroll
    for (int half = 0; half < 2; ++half) {
        #pragma unroll
        for (int n = 0; n < 8; ++n)
            #pragma unroll
            for (int r = 0; r < 4; ++r)
                redO[wv][q_ * 4 + r][n * 16 + m_] =
                    half ? acc1[n][r] : acc0[n][r];
        __syncthreads();
        {
            const int rr  = t >> 4;              // 0..15
            const int c0  = (t & 15) * 8;
            const int row = half * 16 + rr;
            const float li = redL[0][row] + redL[1][row]
                           + redL[2][row] + redL[3][row];
            const float sc = li > 0.f ? 1.f / li : 0.f;   // empty row -> 0
            float4 vA, vB;
            vA.x = redO[0][rr][c0]     + redO[1][rr][c0]     + redO[2][rr][c0]     + redO[3][rr][c0];
            vA.y = redO[0][rr][c0 + 1] + redO[1][rr][c0 + 1] + redO[2][rr][c0 + 1] + redO[3][rr][c0 + 1];
            vA.z = redO[0][rr][c0 + 2] + redO[1][rr][c0 + 2] + redO[2][rr][c0 + 2] + redO[3][rr][c0 + 2];
            vA.w = redO[0][rr][c0 + 3] + redO[1][rr][c0 + 3] + redO[2][rr][c0 + 3] + redO[3][rr][c0 + 3];
            vB.x = redO[0][rr][c0 + 4] + redO[1][rr][c0 + 4] + redO[2][rr][c0 + 4] + redO[3][rr][c0 + 4];
            vB.y = redO[0][rr][c0 + 5] + redO[1][rr][c0 + 5] + redO[2][rr][c0 + 5] + redO[3][rr][c0 + 5];
            vB.z = redO[0][rr][c0 + 6] + redO[1][rr][c0 + 6] + redO[2][rr][c0 + 6] + redO[3][rr][c0 + 6];
            vB.w = redO[0][rr][c0 + 7] + redO[1][rr][c0 + 7] + redO[2][rr][c0 + 7] + redO[3][rr][c0 + 7];
            float* op = out + (((size_t)((b << 11) + i0 + row)) << 7) + c0;
            float4 oA = {vA.x * sc, vA.y * sc, vA.z * sc, vA.w * sc};
            float4 oB = {vB.x * sc, vB.y * sc, vB.z * sc, vB.w * sc};
            *(float4*)op       = oA;
            *(float4*)(op + 4) = oB;
        }
        __syncthreads();
    }
}

extern "C" void kernel_launch(void* const* d_in, const int* in_sizes, int n_in,
                              void* d_out, int out_size, void* d_ws, size_t ws_size,
                              hipStream_t stream) {
    const float* h   = (const float*)d_in[0];
    const int*   adj = (const int*)d_in[1];
    const float* W   = (const float*)d_in[2];
    const float* a   = (const float*)d_in[3];
    float* out = (float*)d_out;

    char* ws = (char*)d_ws;
    _Float16* WhH = (_Float16*)ws;                        // 4 MB
    float* sv = (float*)(ws + (size_t)4 * 1024 * 1024);   // 64 KB
    float* tv = sv + (size_t)B_ * N_;                     // 64 KB

    k_gemm<<<512, 256, 0, stream>>>(h, W, a, WhH, sv, tv);
    k_attn<<<512, 256, 0, stream>>>(WhH, sv, tv, adj, out);
}

// Round 12
// 224.284 us; speedup vs baseline: 1.0234x; 1.0234x over previous
//
#include <hip/hip_runtime.h>
#include <hip/hip_bf16.h>
#include <hip/hip_fp16.h>
#include <math.h>

#define B_ 8
#define N_ 2048
#define F_ 128

typedef __attribute__((ext_vector_type(8))) _Float16 half8;
typedef __attribute__((ext_vector_type(4))) float f32x4;

// ---------------------------------------------------------------------------
// Kernel 1: Wh = h @ W^T (fp32), fp16 B-frag swizzled out; exact fp32 sv/tv.
// WhH layout: element (b, j, o) at ((b*64 + j/32)*128 + o)*32 + ((j/8)%4)*8
// + (j%8)  -> each 32-j chunk is one contiguous 8 KB block.
// ---------------------------------------------------------------------------
__global__ __launch_bounds__(256) void k_gemm(
    const float* __restrict__ h, const float* __restrict__ W,
    const float* __restrict__ a,
    _Float16* __restrict__ WhH, float* __restrict__ sv, float* __restrict__ tv)
{
    __shared__ float h_s[64][129];
    __shared__ float Wt[128][68];
    __shared__ float wsm[128], wtm[128];
    __shared__ float sred[64][4], tred[64][4];

    const int t = threadIdx.x;
    const int rowblk = blockIdx.x >> 1;
    const int ohalf  = blockIdx.x & 1;
    const int r0 = rowblk * 64;

    {
        const int f = (t & 31) * 4;
        #pragma unroll
        for (int it = 0; it < 8; ++it) {
            const int r = (t >> 5) + it * 8;
            float4 v = *(const float4*)&h[(size_t)(r0 + r) * F_ + f];
            h_s[r][f] = v.x; h_s[r][f + 1] = v.y;
            h_s[r][f + 2] = v.z; h_s[r][f + 3] = v.w;
        }
    }
    {
        const int f = (t & 31) * 4;
        #pragma unroll
        for (int it = 0; it < 8; ++it) {
            const int o = (t >> 5) + it * 8;
            float4 v = *(const float4*)&W[(size_t)(ohalf * 64 + o) * F_ + f];
            Wt[f][o] = v.x; Wt[f + 1][o] = v.y;
            Wt[f + 2][o] = v.z; Wt[f + 3][o] = v.w;
        }
    }
    {
        const int f = t & 127;
        const int which = t >> 7;
        const float* av = a + which * 128;
        float acc = 0.f;
        for (int o = 0; o < 128; ++o)
            acc += W[(size_t)o * F_ + f] * av[o];
        if (which == 0) wsm[f] = acc; else wtm[f] = acc;
    }
    __syncthreads();

    const int o4 = t & 15;
    const int r4 = t >> 4;
    float acc[4][4];
    #pragma unroll
    for (int i = 0; i < 4; ++i)
        #pragma unroll
        for (int j = 0; j < 4; ++j) acc[i][j] = 0.f;

    #pragma unroll 4
    for (int k = 0; k < 128; ++k) {
        float4 w = *(const float4*)&Wt[k][o4 * 4];
        float h0 = h_s[r4 * 4 + 0][k];
        float h1 = h_s[r4 * 4 + 1][k];
        float h2 = h_s[r4 * 4 + 2][k];
        float h3 = h_s[r4 * 4 + 3][k];
        acc[0][0] += h0 * w.x; acc[0][1] += h0 * w.y; acc[0][2] += h0 * w.z; acc[0][3] += h0 * w.w;
        acc[1][0] += h1 * w.x; acc[1][1] += h1 * w.y; acc[1][2] += h1 * w.z; acc[1][3] += h1 * w.w;
        acc[2][0] += h2 * w.x; acc[2][1] += h2 * w.y; acc[2][2] += h2 * w.z; acc[2][3] += h2 * w.w;
        acc[3][0] += h3 * w.x; acc[3][1] += h3 * w.y; acc[3][2] += h3 * w.z; acc[3][3] += h3 * w.w;
    }

    {
        const int Rbase = r0 + r4 * 4;
        const int b    = Rbase >> 11;
        const int jj   = Rbase & 2047;
        const int jblk = jj >> 5;
        const int k8   = (jj >> 3) & 3;
        const int kk   = jj & 7;
        #pragma unroll
        for (int jo = 0; jo < 4; ++jo) {
            const int o = ohalf * 64 + o4 * 4 + jo;
            size_t off = ((size_t)(b * 64 + jblk) * 128 + o) * 32 + k8 * 8 + kk;
            union { _Float16 x[4]; uint2 u; } pk;
            pk.x[0] = (_Float16)acc[0][jo];
            pk.x[1] = (_Float16)acc[1][jo];
            pk.x[2] = (_Float16)acc[2][jo];
            pk.x[3] = (_Float16)acc[3][jo];
            *(uint2*)(WhH + off) = pk.u;
        }
    }

    {
        const int r = t & 63, part = t >> 6;
        float as_ = 0.f, at_ = 0.f;
        const int kb = part * 32;
        for (int k = kb; k < kb + 32; ++k) {
            float hv = h_s[r][k];
            as_ += hv * wsm[k];
            at_ += hv * wtm[k];
        }
        sred[r][part] = as_; tred[r][part] = at_;
    }
    __syncthreads();
    if (ohalf == 0 && t < 64) {
        sv[r0 + t] = sred[t][0] + sred[t][1] + sred[t][2] + sred[t][3];
        tv[r0 + t] = tred[t][0] + tred[t][1] + tred[t][2] + tred[t][3];
    }
}

// ---------------------------------------------------------------------------
// Kernel 2: flash-GAT, factorized softmax (no in-loop transcendentals).
// 512 blocks = 8 batch x 64 i-tiles(32 rows); wave wv owns j-slice
// [wv*512,+512) (16 chunks of 32); two A-frags per wave (rows m_, m_+16)
// share every per-lane direct-global B-frag load.  adj prefetched depth-1.
// p = adj ? (E_j>Ethr_i ? C_i*E_j : D_i*F_j) : 0, E/F staged per block
// (2048 exps vs 33.5M).  Direct out via two-pass 32 KB LDS reduce.
// [Best measured config: 226.0 us total; 9 structural variants all 64+-8 us
//  for this kernel with all pipes idle -- practical floor for this harness.]
// ---------------------------------------------------------------------------
__global__ __launch_bounds__(256, 2) void k_attn(
    const _Float16* __restrict__ WhH, const float* __restrict__ sv,
    const float* __restrict__ tv, const int* __restrict__ adj,
    float* __restrict__ out)
{
    __shared__ float  redO[4][16][128];   // 32 KB (two-pass reuse)
    __shared__ float  redL[4][32];
    __shared__ float2 efS[2048];          // 16 KB: (E_j, F_j)
    __shared__ float  tmr[4];

    const int t  = threadIdx.x;
    const int b  = blockIdx.x & 7;        // XCD-swizzle heuristic
    const int i0 = (blockIdx.x >> 3) * 32;
    const float* tb = tv + ((size_t)b << 11);

    // phase 1: per-batch tmax (t-values kept in regs)
    float tv8[8];
    float tm = -INFINITY;
    #pragma unroll
    for (int k = 0; k < 8; ++k) {
        tv8[k] = tb[t + k * 256];
        tm = fmaxf(tm, tv8[k]);
    }
    #pragma unroll
    for (int k = 32; k; k >>= 1) tm = fmaxf(tm, __shfl_xor(tm, k, 64));
    if ((t & 63) == 0) tmr[t >> 6] = tm;
    __syncthreads();
    const float tmax = fmaxf(fmaxf(tmr[0], tmr[1]), fmaxf(tmr[2], tmr[3]));

    // phase 2: E/F table
    #pragma unroll
    for (int k = 0; k < 8; ++k) {
        float d = tv8[k] - tmax;
        efS[t + k * 256] = make_float2(__expf(d), __expf(0.2f * d));
    }

    const int wv   = t >> 6;
    const int lane = t & 63;
    const int m_   = lane & 15;
    const int q_   = lane >> 4;
    const int jbase = wv * 512;

    const int girow0 = (b << 11) + i0 + m_;
    const int girow1 = girow0 + 16;
    const float s0 = sv[girow0];
    const float s1 = sv[girow1];
    const float M0 = fmaxf(s0 + tmax, 0.f);
    const float M1 = fmaxf(s1 + tmax, 0.f);
    const float C0 = __expf(s0 + tmax - M0), D0 = __expf(0.2f * (s0 + tmax) - M0);
    const float C1 = __expf(s1 + tmax - M1), D1 = __expf(0.2f * (s1 + tmax) - M1);
    const float T0 = __expf(-s0 - tmax);
    const float T1 = __expf(-s1 - tmax);

    const int* arow0 = adj + ((size_t)girow0 << 11) + jbase + q_ * 8;
    const int* arow1 = adj + ((size_t)girow1 << 11) + jbase + q_ * 8;
    const _Float16* whc = WhH + (((size_t)b * 64 + wv * 16) << 12)
                        + (size_t)m_ * 32 + q_ * 8;

    f32x4 acc0[8], acc1[8];
    #pragma unroll
    for (int n = 0; n < 8; ++n) {
        acc0[n] = (f32x4){0.f, 0.f, 0.f, 0.f};
        acc1[n] = (f32x4){0.f, 0.f, 0.f, 0.f};
    }
    float lsum0 = 0.f, lsum1 = 0.f;

    __syncthreads();   // efS visible

    int4 a0L = *(const int4*)(arow0), a0H = *(const int4*)(arow0 + 4);
    int4 a1L = *(const int4*)(arow1), a1H = *(const int4*)(arow1 + 4);

    for (int jj = 0; jj < 16; ++jj) {
        const int nxt = (jj + 1) & 15;                 // wrap: harmless
        int4 n0L = *(const int4*)(arow0 + nxt * 32);
        int4 n0H = *(const int4*)(arow0 + nxt * 32 + 4);
        int4 n1L = *(const int4*)(arow1 + nxt * 32);
        int4 n1H = *(const int4*)(arow1 + nxt * 32 + 4);

        // B fragments (direct global, 16B/lane)
        const _Float16* wb = whc + ((size_t)jj << 12);
        half8 bf[8];
        #pragma unroll
        for (int n = 0; n < 8; ++n) bf[n] = *(const half8*)(wb + n * 512);

        // E/F for this lane's 8 k's
        const float4* efp = (const float4*)&efS[jbase + jj * 32 + q_ * 8];
        float4 v0 = efp[0], v1 = efp[1], v2 = efp[2], v3 = efp[3];
        float Ek[8] = {v0.x, v0.z, v1.x, v1.z, v2.x, v2.z, v3.x, v3.z};
        float Fk[8] = {v0.y, v0.w, v1.y, v1.w, v2.y, v2.w, v3.y, v3.w};
        int  a0k[8] = {a0L.x, a0L.y, a0L.z, a0L.w, a0H.x, a0H.y, a0H.z, a0H.w};
        int  a1k[8] = {a1L.x, a1L.y, a1L.z, a1L.w, a1H.x, a1H.y, a1H.z, a1H.w};

        half8 af0, af1;
        #pragma unroll
        for (int k = 0; k < 8; ++k) {
            float p0 = (Ek[k] > T0) ? C0 * Ek[k] : D0 * Fk[k];
            p0 = a0k[k] ? p0 : 0.f;
            float p1 = (Ek[k] > T1) ? C1 * Ek[k] : D1 * Fk[k];
            p1 = a1k[k] ? p1 : 0.f;
            lsum0 += p0; lsum1 += p1;
            af0[k] = (_Float16)p0; af1[k] = (_Float16)p1;
        }

        #pragma unroll
        for (int n = 0; n < 8; ++n) {
            acc0[n] = __builtin_amdgcn_mfma_f32_16x16x32_f16(af0, bf[n], acc0[n], 0, 0, 0);
            acc1[n] = __builtin_amdgcn_mfma_f32_16x16x32_f16(af1, bf[n], acc1[n], 0, 0, 0);
        }
        a0L = n0L; a0H = n0H; a1L = n1L; a1H = n1H;
    }

    // partial l over k-lanes (bits 4,5)
    lsum0 += __shfl_xor(lsum0, 16, 64); lsum0 += __shfl_xor(lsum0, 32, 64);
    lsum1 += __shfl_xor(lsum1, 16, 64); lsum1 += __shfl_xor(lsum1, 32, 64);
    if (q_ == 0) { redL[wv][m_] = lsum0; redL[wv][16 + m_] = lsum1; }
    __syncthreads();

    // two-pass cross-wave reduce + direct out.
    // C/D layout: row = q_*4 + r, col = n*16 + m_.
    #pragma unroll
    for (int half = 0; half < 2; ++half) {
        #pragma unroll
        for (int n = 0; n < 8; ++n)
            #pragma unroll
            for (int r = 0; r < 4; ++r)
                redO[wv][q_ * 4 + r][n * 16 + m_] =
                    half ? acc1[n][r] : acc0[n][r];
        __syncthreads();
        {
            const int rr  = t >> 4;              // 0..15
            const int c0  = (t & 15) * 8;
            const int row = half * 16 + rr;
            const float li = redL[0][row] + redL[1][row]
                           + redL[2][row] + redL[3][row];
            const float sc = li > 0.f ? 1.f / li : 0.f;   // empty row -> 0
            float4 vA, vB;
            vA.x = redO[0][rr][c0]     + redO[1][rr][c0]     + redO[2][rr][c0]     + redO[3][rr][c0];
            vA.y = redO[0][rr][c0 + 1] + redO[1][rr][c0 + 1] + redO[2][rr][c0 + 1] + redO[3][rr][c0 + 1];
            vA.z = redO[0][rr][c0 + 2] + redO[1][rr][c0 + 2] + redO[2][rr][c0 + 2] + redO[3][rr][c0 + 2];
            vA.w = redO[0][rr][c0 + 3] + redO[1][rr][c0 + 3] + redO[2][rr][c0 + 3] + redO[3][rr][c0 + 3];
            vB.x = redO[0][rr][c0 + 4] + redO[1][rr][c0 + 4] + redO[2][rr][c0 + 4] + redO[3][rr][c0 + 4];
            vB.y = redO[0][rr][c0 + 5] + redO[1][rr][c0 + 5] + redO[2][rr][c0 + 5] + redO[3][rr][c0 + 5];
            vB.z = redO[0][rr][c0 + 6] + redO[1][rr][c0 + 6] + redO[2][rr][c0 + 6] + redO[3][rr][c0 + 6];
            vB.w = redO[0][rr][c0 + 7] + redO[1][rr][c0 + 7] + redO[2][rr][c0 + 7] + redO[3][rr][c0 + 7];
            float* op = out + (((size_t)((b << 11) + i0 + row)) << 7) + c0;
            float4 oA = {vA.x * sc, vA.y * sc, vA.z * sc, vA.w * sc};
            float4 oB = {vB.x * sc, vB.y * sc, vB.z * sc, vB.w * sc};
            *(float4*)op       = oA;
            *(float4*)(op + 4) = oB;
        }
        __syncthreads();
    }
}

extern "C" void kernel_launch(void* const* d_in, const int* in_sizes, int n_in,
                              void* d_out, int out_size, void* d_ws, size_t ws_size,
                              hipStream_t stream) {
    const float* h   = (const float*)d_in[0];
    const int*   adj = (const int*)d_in[1];
    const float* W   = (const float*)d_in[2];
    const float* a   = (const float*)d_in[3];
    float* out = (float*)d_out;

    char* ws = (char*)d_ws;
    _Float16* WhH = (_Float16*)ws;                        // 4 MB
    float* sv = (float*)(ws + (size_t)4 * 1024 * 1024);   // 64 KB
    float* tv = sv + (size_t)B_ * N_;                     // 64 KB

    k_gemm<<<512, 256, 0, stream>>>(h, W, a, WhH, sv, tv);
    k_attn<<<512, 256, 0, stream>>>(WhH, sv, tv, adj, out);
}